// Round 1
// baseline (710.322 us; speedup 1.0000x reference)
//
#include <hip/hip_runtime.h>
#include <hip/hip_bf16.h>
#include <stdint.h>

#define F 128
#define R 6
#define NTYPES 95
#define MTILE 128
#define HPAD 136   // 128 + 8 bf16 pad -> 272B row stride, kills ds_read_b128 bank conflicts

typedef short bf16x8 __attribute__((ext_vector_type(8)));
typedef float floatx4 __attribute__((ext_vector_type(4)));

__device__ __forceinline__ unsigned short f2bf(float x) {
    union { float f; unsigned u; } cv; cv.f = x;
    unsigned u = cv.u;
    return (unsigned short)((u + 0x7FFFu + ((u >> 16) & 1u)) >> 16);  // RNE
}

__device__ __forceinline__ float swishf(float x) {
    return x / (1.0f + __expf(-x));
}

// blocks 0..94: embW[z][0:128]=emb[z]@W[0:128], embW[z][128:256]=emb[z]@W[128:256] (fp32)
// blocks 95..158: w2t[n][k] = bf16(W[256+k][n])  (transposed K-contiguous for MFMA B-frags)
__global__ void prep_kernel(const float* __restrict__ emb,
                            const float* __restrict__ W,
                            float* __restrict__ embW,
                            unsigned short* __restrict__ w2t) {
    int t = threadIdx.x;
    int b = blockIdx.x;
    if (b < NTYPES) {
        int c = t >> 7, f = t & 127;
        const float* er = emb + b * F;
        const float* Wc = W + c * F * F;
        float a = 0.f;
        #pragma unroll 8
        for (int k = 0; k < F; ++k) a = __builtin_fmaf(er[k], Wc[k * F + f], a);
        embW[b * 256 + c * F + f] = a;
    } else {
        int idx = (b - NTYPES) * 256 + t;  // 0..16383
        int n = idx >> 7, k = idx & 127;
        w2t[n * F + k] = f2bf(W[(256 + k) * F + n]);
    }
}

__global__ __launch_bounds__(256) void
edge_kernel(const int* __restrict__ Z,
            const float* __restrict__ rbf,
            const int* __restrict__ idnb_i,
            const int* __restrict__ idnb_j,
            const float* __restrict__ W_rbf,
            const float* __restrict__ b_rbf,
            const float* __restrict__ bvec,
            const float* __restrict__ embW,
            const unsigned short* __restrict__ w2t,
            float* __restrict__ out,
            int E) {
    __shared__ __align__(16) short h_bf[MTILE * HPAD]; // 34816 B, A-operand tile (bf16)
    __shared__ float rbf_s[MTILE * R];
    __shared__ int zi_s[MTILE];
    __shared__ int zj_s[MTILE];
    __shared__ float bs[F];

    int t = threadIdx.x;
    int blk = blockIdx.x;
    long ebase = (long)blk * MTILE;

    // ---- stage: rbf (coalesced, 768 floats), Z-gathers, bias ----
    #pragma unroll
    for (int i = 0; i < 3; ++i) {
        int idx = i * 256 + t;
        long g = ebase * R + idx;
        rbf_s[idx] = (g < (long)E * R) ? rbf[g] : 0.f;
    }
    if (t < MTILE) {
        long e = ebase + t;
        long ec = (e < (long)E) ? e : 0;
        zi_s[t] = Z[idnb_i[ec]];
        zj_s[t] = Z[idnb_j[ec]];
    }
    if (t < F) bs[t] = bvec[t];

    // W_rbf columns for this thread's 2 features (registers)
    int fpair = t & 63;
    int f0 = fpair * 2;
    float wr0[R], wr1[R];
    #pragma unroll
    for (int r = 0; r < R; ++r) {
        wr0[r] = W_rbf[r * F + f0];
        wr1[r] = W_rbf[r * F + f0 + 1];
    }
    float brb0 = b_rbf[f0], brb1 = b_rbf[f0 + 1];

    __syncthreads();

    // ---- compute rbf_h tile -> h_bf (each wave: 32 edges, 2 features/thread) ----
    int eg = t >> 6;
    for (int it = 0; it < 32; ++it) {
        int e = eg * 32 + it;
        const float* rp = rbf_s + e * R;  // wave-uniform -> LDS broadcast
        float v0 = brb0, v1 = brb1;
        #pragma unroll
        for (int r = 0; r < R; ++r) {
            float rv = rp[r];
            v0 = __builtin_fmaf(rv, wr0[r], v0);
            v1 = __builtin_fmaf(rv, wr1[r], v1);
        }
        v0 = swishf(v0); v1 = swishf(v1);
        unsigned packed = (unsigned)f2bf(v0) | ((unsigned)f2bf(v1) << 16);
        *(unsigned*)(&h_bf[e * HPAD + f0]) = packed;
    }

    __syncthreads();

    // ---- MFMA: rbf_h[128x128] @ W2[128x128], 16x16x32 bf16 ----
    int w = t >> 6;
    int lid = t & 63;
    int quad = lid >> 4;
    int l15 = lid & 15;
    int wbase = w * 32;

    floatx4 acc[2][8];
    #pragma unroll
    for (int rt = 0; rt < 2; ++rt)
        #pragma unroll
        for (int c = 0; c < 8; ++c)
            acc[rt][c] = (floatx4){0.f, 0.f, 0.f, 0.f};

    const bf16x8* w2v = (const bf16x8*)w2t;  // [n][k] rows of 128 bf16 = 16 chunks
    #pragma unroll
    for (int ks = 0; ks < 4; ++ks) {
        // A-frag: A[m=l15][k=quad*8+j]
        bf16x8 a0 = *(const bf16x8*)(&h_bf[(wbase + l15) * HPAD + ks * 32 + quad * 8]);
        bf16x8 a1 = *(const bf16x8*)(&h_bf[(wbase + 16 + l15) * HPAD + ks * 32 + quad * 8]);
        #pragma unroll
        for (int c = 0; c < 8; ++c) {
            // B-frag: B[k=quad*8+j][n=c*16+l15] = w2t[n][k] (L1-resident 32KB table)
            bf16x8 bfr = w2v[(c * 16 + l15) * 16 + ks * 4 + quad];
            acc[0][c] = __builtin_amdgcn_mfma_f32_16x16x32_bf16(a0, bfr, acc[0][c], 0, 0, 0);
            acc[1][c] = __builtin_amdgcn_mfma_f32_16x16x32_bf16(a1, bfr, acc[1][c], 0, 0, 0);
        }
    }

    // ---- epilogue: + embW0[zi] + embW1[zj] + b, swish, store ----
    // C/D layout: col = c*16 + (lane&15), row = quad*4 + reg
    #pragma unroll
    for (int rt = 0; rt < 2; ++rt) {
        #pragma unroll
        for (int rg = 0; rg < 4; ++rg) {
            int e_loc = wbase + rt * 16 + quad * 4 + rg;
            long e_g = ebase + e_loc;
            bool ok = e_g < (long)E;
            int zi = zi_s[e_loc], zj = zj_s[e_loc];
            const float* p0 = embW + zi * 256;        // x1 @ W0 row
            const float* p1 = embW + zj * 256 + F;    // x2 @ W1 row
            float* op = out + e_g * F;
            #pragma unroll
            for (int c = 0; c < 8; ++c) {
                int f = c * 16 + l15;
                float v = acc[rt][c][rg] + p0[f] + p1[f] + bs[f];
                v = swishf(v);
                if (ok) op[f] = v;
            }
        }
    }
}

extern "C" void kernel_launch(void* const* d_in, const int* in_sizes, int n_in,
                              void* d_out, int out_size, void* d_ws, size_t ws_size,
                              hipStream_t stream) {
    const int*   Z     = (const int*)d_in[0];
    const float* rbf   = (const float*)d_in[1];
    const int*   id_i  = (const int*)d_in[2];
    const int*   id_j  = (const int*)d_in[3];
    const float* emb   = (const float*)d_in[4];
    const float* W_rbf = (const float*)d_in[5];
    const float* b_rbf = (const float*)d_in[6];
    const float* W     = (const float*)d_in[7];
    const float* bvec  = (const float*)d_in[8];
    float* out = (float*)d_out;
    int E = in_sizes[2];

    float* embW = (float*)d_ws;                                   // 95*256*4 = 97280 B
    unsigned short* w2t = (unsigned short*)((char*)d_ws + 97280); // 128*128*2 = 32768 B

    prep_kernel<<<NTYPES + 64, 256, 0, stream>>>(emb, W, embW, w2t);
    int grid = (E + MTILE - 1) / MTILE;
    edge_kernel<<<grid, 256, 0, stream>>>(Z, rbf, id_i, id_j, W_rbf, b_rbf, bvec,
                                          embW, w2t, out, E);
}